// Round 1
// baseline (58.233 us; speedup 1.0000x reference)
//
#include <hip/hip_runtime.h>
#include <cstddef>

// ---------------------------------------------------------------------------
// TCFPEmbedding: out[i,:] = fake_quantize_tcfp12(weight[indices[i], :])
//   per 64-elem block: scale = max(min(absmax, 3*std), 1e-12)
//   q    = clip(rint(x/scale*127), -127, 127); main = q*(scale/127)
//   res  = x - main; rmax = max(absmax(res), 1e-12)
//   idx  = searchsorted(NF4_MIDPOINTS, res/rmax, side='left')  (strict mid < rn)
//   out  = main + NF4_LEVELS[idx]*rmax
// Mapping: 1 block (192 thr = 3 waves) per row of 768 f32; 1 float4 per lane;
// each lane's 4 elems share one 64-elem quant block -> 16-lane shuffle reduce.
// ---------------------------------------------------------------------------

namespace {

constexpr float kL[16] = {
    -1.0f, -0.6961928009986877f, -0.5250730514526367f, -0.39491748809814453f,
    -0.28444138169288635f, -0.18477343022823334f, -0.09105003625154495f, 0.0f,
    0.07958029955625534f, 0.16093020141124725f, 0.24611230194568634f,
    0.33791524171829224f, 0.44070982933044434f, 0.5626170039176941f,
    0.8481764793395996f, 1.0f};

} // namespace

__device__ __constant__ float kNF4Levels[16] = {
    -1.0f, -0.6961928009986877f, -0.5250730514526367f, -0.39491748809814453f,
    -0.28444138169288635f, -0.18477343022823334f, -0.09105003625154495f, 0.0f,
    0.07958029955625534f, 0.16093020141124725f, 0.24611230194568634f,
    0.33791524171829224f, 0.44070982933044434f, 0.5626170039176941f,
    0.8481764793395996f, 1.0f};

__device__ __forceinline__ int nf4_index(float rn) {
  // searchsorted(midpoints, rn, side='left') == count(mid < rn)
  int idx = 0;
#pragma unroll
  for (int k = 0; k < 15; ++k) {
    const float mid = (kL[k] + kL[k + 1]) * 0.5f;  // compile-time f32, matches jnp
    idx += (rn > mid) ? 1 : 0;
  }
  return idx;
}

__global__ void __launch_bounds__(192)
tcfp_embedding_kernel(const int* __restrict__ indices,
                      const float* __restrict__ weight,
                      float* __restrict__ out,
                      int dim) {
  __shared__ float lvl[16];  // 16 words -> 16 distinct banks, conflict-free
  const int tid = threadIdx.x;
  if (tid < 16) lvl[tid] = kNF4Levels[tid];
  __syncthreads();

  const int row  = blockIdx.x;
  const int lane = tid & 63;
  const int col  = (tid >> 6) * 256 + lane * 4;  // chunk never straddles a row

  const int w = indices[row];  // uniform -> scalar load
  const float4 x =
      *reinterpret_cast<const float4*>(weight + (size_t)w * (size_t)dim + col);

  // ---- block stats (64 consecutive elems = this lane's 16-lane group) ----
  float am = fmaxf(fmaxf(fabsf(x.x), fabsf(x.y)), fmaxf(fabsf(x.z), fabsf(x.w)));
  float s  = (x.x + x.y) + (x.z + x.w);
  float ss = (x.x * x.x + x.y * x.y) + (x.z * x.z + x.w * x.w);
#pragma unroll
  for (int m = 1; m <= 8; m <<= 1) {
    am = fmaxf(am, __shfl_xor(am, m));
    s  += __shfl_xor(s, m);
    ss += __shfl_xor(ss, m);
  }
  const float mean  = s * 0.015625f;                       // /64
  const float var   = fmaxf(ss * 0.015625f - mean * mean, 0.0f);
  const float scale = fmaxf(fminf(am, 3.0f * sqrtf(var)), 1e-12f);
  const float to_q   = 127.0f / scale;  // precise IEEE div, once per block
  const float from_q = scale / 127.0f;

  // ---- int8 main component ----
  const float q0 = fminf(fmaxf(rintf(x.x * to_q), -127.0f), 127.0f);
  const float q1 = fminf(fmaxf(rintf(x.y * to_q), -127.0f), 127.0f);
  const float q2 = fminf(fmaxf(rintf(x.z * to_q), -127.0f), 127.0f);
  const float q3 = fminf(fmaxf(rintf(x.w * to_q), -127.0f), 127.0f);
  const float m0 = q0 * from_q, m1 = q1 * from_q, m2 = q2 * from_q, m3 = q3 * from_q;
  const float r0 = x.x - m0, r1 = x.y - m1, r2 = x.z - m2, r3 = x.w - m3;

  // ---- residual absmax over the 64-elem block ----
  float rm = fmaxf(fmaxf(fabsf(r0), fabsf(r1)), fmaxf(fabsf(r2), fabsf(r3)));
#pragma unroll
  for (int m = 1; m <= 8; m <<= 1) rm = fmaxf(rm, __shfl_xor(rm, m));
  rm = fmaxf(rm, 1e-12f);
  const float invr = 1.0f / rm;  // precise, once per block

  // ---- NF4 residual + combine ----
  const float o0 = fmaf(lvl[nf4_index(r0 * invr)], rm, m0);
  const float o1 = fmaf(lvl[nf4_index(r1 * invr)], rm, m1);
  const float o2 = fmaf(lvl[nf4_index(r2 * invr)], rm, m2);
  const float o3 = fmaf(lvl[nf4_index(r3 * invr)], rm, m3);

  float4 o;
  o.x = o0; o.y = o1; o.z = o2; o.w = o3;
  *reinterpret_cast<float4*>(out + (size_t)row * (size_t)dim + col) = o;
}

extern "C" void kernel_launch(void* const* d_in, const int* in_sizes, int n_in,
                              void* d_out, int out_size, void* d_ws, size_t ws_size,
                              hipStream_t stream) {
  const int*   indices = (const int*)d_in[0];
  const float* weight  = (const float*)d_in[1];
  float*       out     = (float*)d_out;

  const int nrows = in_sizes[0];          // 8*4096 = 32768
  const int dim   = out_size / nrows;     // 768
  const int threads = dim / 4;            // 192 (3 waves; dim % 256 == 0)

  tcfp_embedding_kernel<<<nrows, threads, 0, stream>>>(indices, weight, out, dim);
}

// Round 3
// 55.554 us; speedup vs baseline: 1.0482x; 1.0482x over previous
//
#include <hip/hip_runtime.h>
#include <cstddef>

// ---------------------------------------------------------------------------
// TCFPEmbedding: out[i,:] = fake_quantize_tcfp12(weight[indices[i], :])
//   per 64-elem block: scale = max(min(absmax, 3*std), 1e-12)
//   q    = clip(rint(x/scale*127), -127, 127); main = q*(scale/127)
//   res  = x - main; rmax = max(absmax(res), 1e-12)
//   idx  = searchsorted(NF4_MIDPOINTS, res/rmax, side='left')  (strict mid < rn)
//   out  = main + NF4_LEVELS[idx]*rmax
// Mapping: 1 block (192 thr = 3 waves) per TWO rows of 768 f32; 1 float4 per
// lane per row (two independent loads in flight -> 2x memory parallelism);
// each lane's 4 elems share one 64-elem quant block -> 16-lane shuffle reduce.
// Output via nontemporal stores (write-once stream; keep weight in L2/L3).
// ---------------------------------------------------------------------------

typedef float fx4 __attribute__((ext_vector_type(4)));  // native vector: OK for
                                                        // __builtin_nontemporal_*

namespace {

constexpr float kL[16] = {
    -1.0f, -0.6961928009986877f, -0.5250730514526367f, -0.39491748809814453f,
    -0.28444138169288635f, -0.18477343022823334f, -0.09105003625154495f, 0.0f,
    0.07958029955625534f, 0.16093020141124725f, 0.24611230194568634f,
    0.33791524171829224f, 0.44070982933044434f, 0.5626170039176941f,
    0.8481764793395996f, 1.0f};

} // namespace

__device__ __constant__ float kNF4Levels[16] = {
    -1.0f, -0.6961928009986877f, -0.5250730514526367f, -0.39491748809814453f,
    -0.28444138169288635f, -0.18477343022823334f, -0.09105003625154495f, 0.0f,
    0.07958029955625534f, 0.16093020141124725f, 0.24611230194568634f,
    0.33791524171829224f, 0.44070982933044434f, 0.5626170039176941f,
    0.8481764793395996f, 1.0f};

__device__ __forceinline__ int nf4_index(float rn) {
  // searchsorted(midpoints, rn, side='left') == count(mid < rn)
  int idx = 0;
#pragma unroll
  for (int k = 0; k < 15; ++k) {
    const float mid = (kL[k] + kL[k + 1]) * 0.5f;  // compile-time f32, matches jnp
    idx += (rn > mid) ? 1 : 0;
  }
  return idx;
}

// Full per-row fake-quantize of this thread's 4 elems (one 64-elem quant block
// per 16-lane group). `lvl` is the LDS level table (16 words, conflict-free).
__device__ __forceinline__ fx4 tcfp12_quantize(fx4 x, const float* lvl) {
  // ---- block stats ----
  float am = fmaxf(fmaxf(fabsf(x.x), fabsf(x.y)), fmaxf(fabsf(x.z), fabsf(x.w)));
  float s  = (x.x + x.y) + (x.z + x.w);
  float ss = (x.x * x.x + x.y * x.y) + (x.z * x.z + x.w * x.w);
#pragma unroll
  for (int m = 1; m <= 8; m <<= 1) {
    am = fmaxf(am, __shfl_xor(am, m));
    s  += __shfl_xor(s, m);
    ss += __shfl_xor(ss, m);
  }
  const float mean  = s * 0.015625f;                       // /64
  const float var   = fmaxf(ss * 0.015625f - mean * mean, 0.0f);
  const float scale = fmaxf(fminf(am, 3.0f * sqrtf(var)), 1e-12f);
  const float to_q   = 127.0f / scale;  // precise IEEE div, once per block
  const float from_q = scale / 127.0f;

  // ---- int8 main component ----
  const float q0 = fminf(fmaxf(rintf(x.x * to_q), -127.0f), 127.0f);
  const float q1 = fminf(fmaxf(rintf(x.y * to_q), -127.0f), 127.0f);
  const float q2 = fminf(fmaxf(rintf(x.z * to_q), -127.0f), 127.0f);
  const float q3 = fminf(fmaxf(rintf(x.w * to_q), -127.0f), 127.0f);
  const float m0 = q0 * from_q, m1 = q1 * from_q, m2 = q2 * from_q, m3 = q3 * from_q;
  const float r0 = x.x - m0, r1 = x.y - m1, r2 = x.z - m2, r3 = x.w - m3;

  // ---- residual absmax over the 64-elem block ----
  float rm = fmaxf(fmaxf(fabsf(r0), fabsf(r1)), fmaxf(fabsf(r2), fabsf(r3)));
#pragma unroll
  for (int m = 1; m <= 8; m <<= 1) rm = fmaxf(rm, __shfl_xor(rm, m));
  rm = fmaxf(rm, 1e-12f);
  const float invr = 1.0f / rm;  // precise, once per block

  // ---- NF4 residual + combine ----
  fx4 o;
  o.x = fmaf(lvl[nf4_index(r0 * invr)], rm, m0);
  o.y = fmaf(lvl[nf4_index(r1 * invr)], rm, m1);
  o.z = fmaf(lvl[nf4_index(r2 * invr)], rm, m2);
  o.w = fmaf(lvl[nf4_index(r3 * invr)], rm, m3);
  return o;
}

__global__ void __launch_bounds__(192)
tcfp_embedding_kernel(const int* __restrict__ indices,
                      const float* __restrict__ weight,
                      float* __restrict__ out,
                      int dim, int nrows) {
  __shared__ float lvl[16];  // 16 words -> 16 distinct banks, conflict-free
  const int tid = threadIdx.x;
  if (tid < 16) lvl[tid] = kNF4Levels[tid];
  __syncthreads();

  const int row0 = blockIdx.x * 2;
  const int row1 = row0 + 1;
  const int lane = tid & 63;
  const int col  = (tid >> 6) * 256 + lane * 4;  // chunk never straddles a row
  const bool has1 = (row1 < nrows);

  // Two independent gathers issued back-to-back (2x memory-level parallelism)
  const int w0 = indices[row0];                    // uniform -> scalar load
  const int w1 = has1 ? indices[row1] : w0;
  const fx4 x0 =
      *reinterpret_cast<const fx4*>(weight + (size_t)w0 * (size_t)dim + col);
  const fx4 x1 =
      *reinterpret_cast<const fx4*>(weight + (size_t)w1 * (size_t)dim + col);

  const fx4 o0 = tcfp12_quantize(x0, lvl);
  const fx4 o1 = tcfp12_quantize(x1, lvl);

  // Nontemporal: output is a write-once stream; don't evict weight from L2/L3
  __builtin_nontemporal_store(
      o0, reinterpret_cast<fx4*>(out + (size_t)row0 * (size_t)dim + col));
  if (has1)
    __builtin_nontemporal_store(
        o1, reinterpret_cast<fx4*>(out + (size_t)row1 * (size_t)dim + col));
}

extern "C" void kernel_launch(void* const* d_in, const int* in_sizes, int n_in,
                              void* d_out, int out_size, void* d_ws, size_t ws_size,
                              hipStream_t stream) {
  const int*   indices = (const int*)d_in[0];
  const float* weight  = (const float*)d_in[1];
  float*       out     = (float*)d_out;

  const int nrows = in_sizes[0];          // 8*4096 = 32768
  const int dim   = out_size / nrows;     // 768
  const int threads = dim / 4;            // 192 (3 waves; dim % 256 == 0)
  const int grid = (nrows + 1) / 2;       // 2 rows per block

  tcfp_embedding_kernel<<<grid, threads, 0, stream>>>(indices, weight, out,
                                                      dim, nrows);
}